// Round 1
// baseline (1243.065 us; speedup 1.0000x reference)
//
#include <hip/hip_runtime.h>

#define N_USERS 100000
#define N_ITEMS 50000
#define N_NODES 150000
#define EMBED   64
#define NNZV    4000000
#define BATCH   4096

// ---------------- concat embed_user | embed_item -> E (float4 vectorized) ----
__global__ void k_concat(const float* __restrict__ eu, const float* __restrict__ ei,
                         float* __restrict__ E) {
    int idx = blockIdx.x * blockDim.x + threadIdx.x;       // float4 index
    const int total = N_NODES * (EMBED / 4);               // 2,400,000
    if (idx >= total) return;
    int node = idx / (EMBED / 4);
    int part = idx - node * (EMBED / 4);
    float4 v;
    if (node < N_USERS) v = ((const float4*)eu)[node * (EMBED / 4) + part];
    else                v = ((const float4*)ei)[(node - N_USERS) * (EMBED / 4) + part];
    ((float4*)E)[idx] = v;
}

// ---------------- histogram of row_idx ---------------------------------------
__global__ void k_hist(const int* __restrict__ row, int* __restrict__ counts, int nnz) {
    int i = blockIdx.x * blockDim.x + threadIdx.x;
    if (i < nnz) atomicAdd(&counts[row[i]], 1);
}

// ---------------- block-wise exclusive scan (1024 elems / block) -------------
__global__ void k_scan_blocks(const int* __restrict__ counts, int* __restrict__ row_ptr,
                              int* __restrict__ bsums, int n) {
    __shared__ int s[256];
    int t = threadIdx.x;
    int base = blockIdx.x * 1024 + t * 4;
    int c0 = (base + 0 < n) ? counts[base + 0] : 0;
    int c1 = (base + 1 < n) ? counts[base + 1] : 0;
    int c2 = (base + 2 < n) ? counts[base + 2] : 0;
    int c3 = (base + 3 < n) ? counts[base + 3] : 0;
    int tot = c0 + c1 + c2 + c3;
    s[t] = tot;
    __syncthreads();
    for (int off = 1; off < 256; off <<= 1) {
        int v = (t >= off) ? s[t - off] : 0;
        __syncthreads();
        s[t] += v;
        __syncthreads();
    }
    int excl = s[t] - tot;   // exclusive prefix of this thread's 4 within block
    if (base + 0 < n) row_ptr[base + 0] = excl;
    if (base + 1 < n) row_ptr[base + 1] = excl + c0;
    if (base + 2 < n) row_ptr[base + 2] = excl + c0 + c1;
    if (base + 3 < n) row_ptr[base + 3] = excl + c0 + c1 + c2;
    if (t == 255) bsums[blockIdx.x] = s[255];
}

// ---------------- scan of block sums (single block, nb <= 256) ---------------
__global__ void k_scan_sums(const int* __restrict__ bsums, int* __restrict__ bscan, int nb) {
    __shared__ int s[256];
    int t = threadIdx.x;
    int v = (t < nb) ? bsums[t] : 0;
    s[t] = v;
    __syncthreads();
    for (int off = 1; off < 256; off <<= 1) {
        int u = (t >= off) ? s[t - off] : 0;
        __syncthreads();
        s[t] += u;
        __syncthreads();
    }
    bscan[t] = s[t] - v;     // exclusive
}

// ---------------- add block offsets; init cursor; close row_ptr --------------
__global__ void k_add(int* __restrict__ row_ptr, int* __restrict__ cursor,
                      const int* __restrict__ bscan, int n, int nnz) {
    int i = blockIdx.x * blockDim.x + threadIdx.x;
    if (i == 0) row_ptr[n] = nnz;
    if (i < n) {
        int v = row_ptr[i] + bscan[i >> 10];
        row_ptr[i] = v;
        cursor[i]  = v;
    }
}

// ---------------- scatter edges into CSR order -------------------------------
__global__ void k_scatter(const int* __restrict__ row, const int* __restrict__ col,
                          const float* __restrict__ vals, int* __restrict__ cursor,
                          int* __restrict__ col_s, float* __restrict__ val_s, int nnz) {
    int i = blockIdx.x * blockDim.x + threadIdx.x;
    if (i < nnz) {
        int r = row[i];
        int p = atomicAdd(&cursor[r], 1);
        col_s[p] = col[i];
        val_s[p] = vals[i];
    }
}

// ---------------- SpMM: one wave per row, lane = embed dim -------------------
__global__ void k_spmm(const int* __restrict__ row_ptr, const int* __restrict__ col_s,
                       const float* __restrict__ val_s, const float* __restrict__ Ein,
                       float* __restrict__ Eout) {
    int lane = threadIdx.x & 63;
    int r = blockIdx.x * 4 + (threadIdx.x >> 6);
    if (r >= N_NODES) return;
    int start = row_ptr[r];
    int end   = row_ptr[r + 1];
    float acc = 0.f;
    for (int e0 = start; e0 < end; e0 += 64) {
        int ei = e0 + lane;
        int c = 0; float v = 0.f;
        if (ei < end) { c = col_s[ei]; v = val_s[ei]; }
        int n = min(64, end - e0);
        for (int j = 0; j < n; j++) {
            int   cc = __shfl(c, j);
            float vv = __shfl(v, j);
            acc += vv * Ein[cc * EMBED + lane];
        }
    }
    Eout[r * EMBED + lane] = acc;
}

// ---------------- gather batch rows into out (init or accumulate) ------------
__global__ void k_gather(const int* __restrict__ bu, const int* __restrict__ bp,
                         const int* __restrict__ bn, const float* __restrict__ E,
                         float* __restrict__ out, int init) {
    int lane = threadIdx.x & 63;
    int j = blockIdx.x * 4 + (threadIdx.x >> 6);
    if (j >= 3 * BATCH) return;
    int node;
    if (j < BATCH)          node = bu[j];
    else if (j < 2 * BATCH) node = N_USERS + bp[j - BATCH];
    else                    node = N_USERS + bn[j - 2 * BATCH];
    float v = 0.25f * E[node * EMBED + lane];
    if (init) out[j * EMBED + lane] = v;
    else      out[j * EMBED + lane] += v;
}

extern "C" void kernel_launch(void* const* d_in, const int* in_sizes, int n_in,
                              void* d_out, int out_size, void* d_ws, size_t ws_size,
                              hipStream_t stream) {
    const int*   bu   = (const int*)d_in[0];
    const int*   bp   = (const int*)d_in[1];
    const int*   bn   = (const int*)d_in[2];
    const float* eu   = (const float*)d_in[3];
    const float* ei   = (const float*)d_in[4];
    const int*   row  = (const int*)d_in[5];
    const int*   col  = (const int*)d_in[6];
    const float* vals = (const float*)d_in[7];
    float* out = (float*)d_out;

    // workspace carve-up (all 4-byte units, 256B aligned sections)
    char* p = (char*)d_ws;
    auto alloc = [&](size_t nelem) {
        void* r = (void*)p;
        size_t bytes = (nelem * 4 + 255) & ~(size_t)255;
        p += bytes;
        return r;
    };
    float* E_a     = (float*)alloc((size_t)N_NODES * EMBED);
    float* E_b     = (float*)alloc((size_t)N_NODES * EMBED);
    int*   col_s   = (int*)  alloc(NNZV);
    float* val_s   = (float*)alloc(NNZV);
    int*   row_ptr = (int*)  alloc(N_NODES + 1);
    int*   cursor  = (int*)  alloc(N_NODES);
    int*   counts  = (int*)  alloc(N_NODES);
    int*   bsums   = (int*)  alloc(256);
    int*   bscan   = (int*)  alloc(256);
    (void)ws_size; (void)n_in; (void)in_sizes; (void)out_size;

    const int nnz = NNZV;
    hipMemsetAsync(counts, 0, N_NODES * sizeof(int), stream);

    k_concat<<<(N_NODES * (EMBED / 4) + 255) / 256, 256, 0, stream>>>(eu, ei, E_a);
    k_hist<<<(nnz + 255) / 256, 256, 0, stream>>>(row, counts, nnz);

    int nb = (N_NODES + 1023) / 1024;   // 147
    k_scan_blocks<<<nb, 256, 0, stream>>>(counts, row_ptr, bsums, N_NODES);
    k_scan_sums<<<1, 256, 0, stream>>>(bsums, bscan, nb);
    k_add<<<(N_NODES + 255) / 256, 256, 0, stream>>>(row_ptr, cursor, bscan, N_NODES, nnz);
    k_scatter<<<(nnz + 255) / 256, 256, 0, stream>>>(row, col, vals, cursor, col_s, val_s, nnz);

    // out = 0.25 * E0[batch]
    k_gather<<<(3 * BATCH + 3) / 4, 256, 0, stream>>>(bu, bp, bn, E_a, out, 1);

    float* cur = E_a;
    float* nxt = E_b;
    for (int l = 0; l < 3; l++) {
        k_spmm<<<(N_NODES + 3) / 4, 256, 0, stream>>>(row_ptr, col_s, val_s, cur, nxt);
        k_gather<<<(3 * BATCH + 3) / 4, 256, 0, stream>>>(bu, bp, bn, nxt, out, 0);
        float* t = cur; cur = nxt; nxt = t;
    }
}

// Round 3
// 929.417 us; speedup vs baseline: 1.3375x; 1.3375x over previous
//
#include <hip/hip_runtime.h>

#define N_USERS 100000
#define N_ITEMS 50000
#define N_NODES 150000
#define EMBED   64
#define NNZV    4000000
#define BATCH   4096

// ---------------- concat embed_user | embed_item -> E (float4 vectorized) ----
__global__ void k_concat(const float* __restrict__ eu, const float* __restrict__ ei,
                         float* __restrict__ E) {
    int idx = blockIdx.x * blockDim.x + threadIdx.x;       // float4 index
    const int total = N_NODES * (EMBED / 4);               // 2,400,000
    if (idx >= total) return;
    int node = idx / (EMBED / 4);
    int part = idx - node * (EMBED / 4);
    float4 v;
    if (node < N_USERS) v = ((const float4*)eu)[node * (EMBED / 4) + part];
    else                v = ((const float4*)ei)[(node - N_USERS) * (EMBED / 4) + part];
    ((float4*)E)[idx] = v;
}

// ---------------- histogram of row_idx ---------------------------------------
__global__ void k_hist(const int* __restrict__ row, int* __restrict__ counts, int nnz) {
    int i = blockIdx.x * blockDim.x + threadIdx.x;
    if (i < nnz) atomicAdd(&counts[row[i]], 1);
}

// ---------------- block-wise exclusive scan (1024 elems / block) -------------
__global__ void k_scan_blocks(const int* __restrict__ counts, int* __restrict__ row_ptr,
                              int* __restrict__ bsums, int n) {
    __shared__ int s[256];
    int t = threadIdx.x;
    int base = blockIdx.x * 1024 + t * 4;
    int c0 = (base + 0 < n) ? counts[base + 0] : 0;
    int c1 = (base + 1 < n) ? counts[base + 1] : 0;
    int c2 = (base + 2 < n) ? counts[base + 2] : 0;
    int c3 = (base + 3 < n) ? counts[base + 3] : 0;
    int tot = c0 + c1 + c2 + c3;
    s[t] = tot;
    __syncthreads();
    for (int off = 1; off < 256; off <<= 1) {
        int v = (t >= off) ? s[t - off] : 0;
        __syncthreads();
        s[t] += v;
        __syncthreads();
    }
    int excl = s[t] - tot;
    if (base + 0 < n) row_ptr[base + 0] = excl;
    if (base + 1 < n) row_ptr[base + 1] = excl + c0;
    if (base + 2 < n) row_ptr[base + 2] = excl + c0 + c1;
    if (base + 3 < n) row_ptr[base + 3] = excl + c0 + c1 + c2;
    if (t == 255) bsums[blockIdx.x] = s[255];
}

// ---------------- scan of block sums (single block, nb <= 256) ---------------
__global__ void k_scan_sums(const int* __restrict__ bsums, int* __restrict__ bscan, int nb) {
    __shared__ int s[256];
    int t = threadIdx.x;
    int v = (t < nb) ? bsums[t] : 0;
    s[t] = v;
    __syncthreads();
    for (int off = 1; off < 256; off <<= 1) {
        int u = (t >= off) ? s[t - off] : 0;
        __syncthreads();
        s[t] += u;
        __syncthreads();
    }
    bscan[t] = s[t] - v;
}

// ---------------- add block offsets; init cursor; close row_ptr --------------
__global__ void k_add(int* __restrict__ row_ptr, int* __restrict__ cursor,
                      const int* __restrict__ bscan, int n, int nnz) {
    int i = blockIdx.x * blockDim.x + threadIdx.x;
    if (i == 0) row_ptr[n] = nnz;
    if (i < n) {
        int v = row_ptr[i] + bscan[i >> 10];
        row_ptr[i] = v;
        cursor[i]  = v;
    }
}

// ---------------- scatter edges into CSR order: ONE packed 8B record ---------
__global__ void k_scatter(const int* __restrict__ row, const int* __restrict__ col,
                          const float* __restrict__ vals, int* __restrict__ cursor,
                          unsigned long long* __restrict__ edges, int nnz) {
    int i = blockIdx.x * blockDim.x + threadIdx.x;
    if (i < nnz) {
        int r = row[i];
        unsigned long long rec = (unsigned int)col[i]
                               | ((unsigned long long)__float_as_uint(vals[i]) << 32);
        int p = atomicAdd(&cursor[r], 1);
        edges[p] = rec;
    }
}

// ---------------- SpMM: wave per row, quarter-wave (16 lanes) per edge -------
// lane = g*16 + d. Group g handles chunk-relative edge indices {4k+g}.
// CRITICAL: the inner loop trip count kmax is WAVE-UNIFORM — on AMD, __shfl
// (ds_bpermute) reads from INACTIVE lanes return 0, so a per-group trip count
// silently drops edges (round-2 bug). Overshoot lanes (src >= nleft) hold a
// zero-padded record (vv == 0.0f) so the extra iteration contributes nothing.
__global__ void k_spmm(const int* __restrict__ row_ptr,
                       const unsigned long long* __restrict__ edges,
                       const float4* __restrict__ Ein, float4* __restrict__ Eout) {
    int lane = threadIdx.x & 63;
    int r = blockIdx.x * 4 + (threadIdx.x >> 6);
    if (r >= N_NODES) return;
    int g = lane >> 4;
    int d = lane & 15;
    int start = row_ptr[r];
    int end   = row_ptr[r + 1];
    float4 acc = make_float4(0.f, 0.f, 0.f, 0.f);
    for (int e0 = start; e0 < end; e0 += 64) {
        int ei = e0 + lane;
        unsigned long long rec = 0ull;
        if (ei < end) rec = edges[ei];
        int clo = (int)(rec & 0xffffffffull);
        int vhi = (int)(rec >> 32);
        int nleft = end - e0;                 // 1..64 edges in this chunk (uniform)
        int kmax = (nleft + 3) >> 2;          // uniform across the wave
        #pragma unroll 4
        for (int k = 0; k < kmax; k++) {
            int src = 4 * k + g;              // may exceed nleft-1: vv==0 then
            int cc = __shfl(clo, src);
            float vv = __int_as_float(__shfl(vhi, src));
            float4 e = Ein[cc * 16 + d];
            acc.x += vv * e.x;
            acc.y += vv * e.y;
            acc.z += vv * e.z;
            acc.w += vv * e.w;
        }
    }
    // reduce the 4 group partials (stride-16 lanes hold same d)
    acc.x += __shfl_xor(acc.x, 16);
    acc.y += __shfl_xor(acc.y, 16);
    acc.z += __shfl_xor(acc.z, 16);
    acc.w += __shfl_xor(acc.w, 16);
    acc.x += __shfl_xor(acc.x, 32);
    acc.y += __shfl_xor(acc.y, 32);
    acc.z += __shfl_xor(acc.z, 32);
    acc.w += __shfl_xor(acc.w, 32);
    if (lane < 16) Eout[r * 16 + lane] = acc;
}

// ---------------- gather batch rows into out (init or accumulate), float4 ----
__global__ void k_gather(const int* __restrict__ bu, const int* __restrict__ bp,
                         const int* __restrict__ bn, const float4* __restrict__ E,
                         float4* __restrict__ out, int init) {
    int idx = blockIdx.x * blockDim.x + threadIdx.x;      // float4 index
    if (idx >= 3 * BATCH * 16) return;
    int j = idx >> 4;
    int d = idx & 15;
    int node;
    if (j < BATCH)          node = bu[j];
    else if (j < 2 * BATCH) node = N_USERS + bp[j - BATCH];
    else                    node = N_USERS + bn[j - 2 * BATCH];
    float4 v = E[node * 16 + d];
    v.x *= 0.25f; v.y *= 0.25f; v.z *= 0.25f; v.w *= 0.25f;
    if (init) {
        out[idx] = v;
    } else {
        float4 o = out[idx];
        o.x += v.x; o.y += v.y; o.z += v.z; o.w += v.w;
        out[idx] = o;
    }
}

extern "C" void kernel_launch(void* const* d_in, const int* in_sizes, int n_in,
                              void* d_out, int out_size, void* d_ws, size_t ws_size,
                              hipStream_t stream) {
    const int*   bu   = (const int*)d_in[0];
    const int*   bp   = (const int*)d_in[1];
    const int*   bn   = (const int*)d_in[2];
    const float* eu   = (const float*)d_in[3];
    const float* ei   = (const float*)d_in[4];
    const int*   row  = (const int*)d_in[5];
    const int*   col  = (const int*)d_in[6];
    const float* vals = (const float*)d_in[7];
    float* out = (float*)d_out;

    char* p = (char*)d_ws;
    auto alloc = [&](size_t nbytes) {
        void* r = (void*)p;
        p += (nbytes + 255) & ~(size_t)255;
        return r;
    };
    float*              E_a     = (float*)alloc((size_t)N_NODES * EMBED * 4);
    float*              E_b     = (float*)alloc((size_t)N_NODES * EMBED * 4);
    unsigned long long* edges   = (unsigned long long*)alloc((size_t)NNZV * 8);
    int*                row_ptr = (int*)alloc((N_NODES + 1) * 4);
    int*                cursor  = (int*)alloc(N_NODES * 4);
    int*                counts  = (int*)alloc(N_NODES * 4);
    int*                bsums   = (int*)alloc(256 * 4);
    int*                bscan   = (int*)alloc(256 * 4);
    (void)ws_size; (void)n_in; (void)in_sizes; (void)out_size;

    const int nnz = NNZV;
    hipMemsetAsync(counts, 0, N_NODES * sizeof(int), stream);

    k_concat<<<(N_NODES * (EMBED / 4) + 255) / 256, 256, 0, stream>>>(eu, ei, E_a);
    k_hist<<<(nnz + 255) / 256, 256, 0, stream>>>(row, counts, nnz);

    int nb = (N_NODES + 1023) / 1024;
    k_scan_blocks<<<nb, 256, 0, stream>>>(counts, row_ptr, bsums, N_NODES);
    k_scan_sums<<<1, 256, 0, stream>>>(bsums, bscan, nb);
    k_add<<<(N_NODES + 255) / 256, 256, 0, stream>>>(row_ptr, cursor, bscan, N_NODES, nnz);
    k_scatter<<<(nnz + 255) / 256, 256, 0, stream>>>(row, col, vals, cursor, edges, nnz);

    k_gather<<<(3 * BATCH * 16 + 255) / 256, 256, 0, stream>>>(
        bu, bp, bn, (const float4*)E_a, (float4*)out, 1);

    float* cur = E_a;
    float* nxt = E_b;
    for (int l = 0; l < 3; l++) {
        k_spmm<<<(N_NODES + 3) / 4, 256, 0, stream>>>(
            row_ptr, edges, (const float4*)cur, (float4*)nxt);
        k_gather<<<(3 * BATCH * 16 + 255) / 256, 256, 0, stream>>>(
            bu, bp, bn, (const float4*)nxt, (float4*)out, 0);
        float* t = cur; cur = nxt; nxt = t;
    }
}

// Round 4
// 864.684 us; speedup vs baseline: 1.4376x; 1.0749x over previous
//
#include <hip/hip_runtime.h>

#define N_USERS 100000
#define N_ITEMS 50000
#define N_NODES 150000
#define EMBED   64
#define NNZV    4000000
#define BATCH   4096
// bucket = row >> 9 : 512 rows per bucket, ceil(150000/512) = 293 buckets
#define NBKT    293

// ---------------- concat embed_user | embed_item -> E (float4 vectorized) ----
__global__ void k_concat(const float* __restrict__ eu, const float* __restrict__ ei,
                         float* __restrict__ E) {
    int idx = blockIdx.x * blockDim.x + threadIdx.x;       // float4 index
    const int total = N_NODES * (EMBED / 4);
    if (idx >= total) return;
    int node = idx / (EMBED / 4);
    int part = idx - node * (EMBED / 4);
    float4 v;
    if (node < N_USERS) v = ((const float4*)eu)[node * (EMBED / 4) + part];
    else                v = ((const float4*)ei)[(node - N_USERS) * (EMBED / 4) + part];
    ((float4*)E)[idx] = v;
}

// ---------------- histogram of row_idx ---------------------------------------
__global__ void k_hist(const int* __restrict__ row, int* __restrict__ counts, int nnz) {
    int i = blockIdx.x * blockDim.x + threadIdx.x;
    if (i < nnz) atomicAdd(&counts[row[i]], 1);
}

// ---------------- block-wise exclusive scan (1024 elems / block) -------------
__global__ void k_scan_blocks(const int* __restrict__ counts, int* __restrict__ row_ptr,
                              int* __restrict__ bsums, int n) {
    __shared__ int s[256];
    int t = threadIdx.x;
    int base = blockIdx.x * 1024 + t * 4;
    int c0 = (base + 0 < n) ? counts[base + 0] : 0;
    int c1 = (base + 1 < n) ? counts[base + 1] : 0;
    int c2 = (base + 2 < n) ? counts[base + 2] : 0;
    int c3 = (base + 3 < n) ? counts[base + 3] : 0;
    int tot = c0 + c1 + c2 + c3;
    s[t] = tot;
    __syncthreads();
    for (int off = 1; off < 256; off <<= 1) {
        int v = (t >= off) ? s[t - off] : 0;
        __syncthreads();
        s[t] += v;
        __syncthreads();
    }
    int excl = s[t] - tot;
    if (base + 0 < n) row_ptr[base + 0] = excl;
    if (base + 1 < n) row_ptr[base + 1] = excl + c0;
    if (base + 2 < n) row_ptr[base + 2] = excl + c0 + c1;
    if (base + 3 < n) row_ptr[base + 3] = excl + c0 + c1 + c2;
    if (t == 255) bsums[blockIdx.x] = s[255];
}

// ---------------- scan of block sums (single block, nb <= 256) ---------------
__global__ void k_scan_sums(const int* __restrict__ bsums, int* __restrict__ bscan, int nb) {
    __shared__ int s[256];
    int t = threadIdx.x;
    int v = (t < nb) ? bsums[t] : 0;
    s[t] = v;
    __syncthreads();
    for (int off = 1; off < 256; off <<= 1) {
        int u = (t >= off) ? s[t - off] : 0;
        __syncthreads();
        s[t] += u;
        __syncthreads();
    }
    bscan[t] = s[t] - v;
}

// -------- add block offsets; init cursor + per-bucket cursors; close ---------
__global__ void k_add(int* __restrict__ row_ptr, int* __restrict__ cursor,
                      int* __restrict__ bcur, const int* __restrict__ bscan,
                      int n, int nnz) {
    int i = blockIdx.x * blockDim.x + threadIdx.x;
    if (i == 0) row_ptr[n] = nnz;
    if (i < n) {
        int v = row_ptr[i] + bscan[i >> 10];
        row_ptr[i] = v;
        cursor[i]  = v;
        if ((i & 511) == 0) bcur[i >> 9] = v;   // bucket base = row_ptr[b<<9]
    }
}

// ---------------- Phase A: partition edges into 512-row buckets --------------
// Record: low32 = (r&511)<<18 | col (col < 2^18), high32 = val bits.
// Per-tile LDS histogram -> ONE global atomic per (block,bucket) -> runs of
// ~56 consecutive records per bucket: writes are line-local, not random.
__global__ __launch_bounds__(512) void k_parta(
        const int* __restrict__ row, const int* __restrict__ col,
        const float* __restrict__ vals, int* __restrict__ bcur,
        unsigned long long* __restrict__ staging, int nnz) {
    __shared__ int cnt[512];
    __shared__ int base_s[512];
    int tid = threadIdx.x;
    cnt[tid] = 0;
    __syncthreads();
    int tile0 = blockIdx.x * 16384;
    for (int k = 0; k < 32; k++) {
        int e = tile0 + k * 512 + tid;
        if (e < nnz) atomicAdd(&cnt[row[e] >> 9], 1);
    }
    __syncthreads();
    int c_ = cnt[tid];
    base_s[tid] = c_ ? atomicAdd(&bcur[tid], c_) : 0;   // reserve contiguous run
    __syncthreads();
    cnt[tid] = 0;                                       // reuse as rank counter
    __syncthreads();
    for (int k = 0; k < 32; k++) {
        int e = tile0 + k * 512 + tid;
        if (e < nnz) {
            int r = row[e];
            int b = r >> 9;
            int rank = atomicAdd(&cnt[b], 1);
            unsigned int key = ((unsigned int)(r & 511) << 18) | (unsigned int)col[e];
            unsigned long long rec = (unsigned long long)key
                                   | ((unsigned long long)__float_as_uint(vals[e]) << 32);
            staging[base_s[b] + rank] = rec;
        }
    }
}

// ---------------- Phase B: bucket-local scatter to final CSR slots -----------
// One block per bucket: random writes confined to a ~110 KB window owned by
// ONE XCD's L2 -> lines fill completely before eviction.
__global__ void k_partb(const int* __restrict__ row_ptr,
                        const unsigned long long* __restrict__ staging,
                        int* __restrict__ cursor,
                        unsigned long long* __restrict__ edges) {
    int b = blockIdx.x;
    int rbase = b << 9;
    int endrow = rbase + 512; if (endrow > N_NODES) endrow = N_NODES;
    int start = row_ptr[rbase];
    int end   = row_ptr[endrow];
    for (int i = start + threadIdx.x; i < end; i += blockDim.x) {
        unsigned long long rec = staging[i];
        unsigned int key = (unsigned int)rec;
        int r = rbase + (int)(key >> 18);
        unsigned int c = key & 0x3FFFFu;
        int p = atomicAdd(&cursor[r], 1);
        edges[p] = (rec & 0xFFFFFFFF00000000ull) | c;   // (valbits<<32)|col
    }
}

// ---------------- SpMM: wave per row, quarter-wave (16 lanes) per edge -------
// Inner trip count kmax is WAVE-UNIFORM: on AMD, __shfl (ds_bpermute) from
// INACTIVE lanes returns 0 (round-2 bug). Overshoot lanes hold zero-padded
// records (vv==0) so extra iterations are harmless.
__global__ void k_spmm(const int* __restrict__ row_ptr,
                       const unsigned long long* __restrict__ edges,
                       const float4* __restrict__ Ein, float4* __restrict__ Eout) {
    int lane = threadIdx.x & 63;
    int r = blockIdx.x * 4 + (threadIdx.x >> 6);
    if (r >= N_NODES) return;
    int g = lane >> 4;
    int d = lane & 15;
    int start = row_ptr[r];
    int end   = row_ptr[r + 1];
    float4 acc = make_float4(0.f, 0.f, 0.f, 0.f);
    for (int e0 = start; e0 < end; e0 += 64) {
        int ei = e0 + lane;
        unsigned long long rec = 0ull;
        if (ei < end) rec = edges[ei];
        int clo = (int)(rec & 0xffffffffull);
        int vhi = (int)(rec >> 32);
        int nleft = end - e0;
        int kmax = (nleft + 3) >> 2;          // uniform across the wave
        #pragma unroll 4
        for (int k = 0; k < kmax; k++) {
            int src = 4 * k + g;
            int cc = __shfl(clo, src);
            float vv = __int_as_float(__shfl(vhi, src));
            float4 e = Ein[cc * 16 + d];
            acc.x += vv * e.x;
            acc.y += vv * e.y;
            acc.z += vv * e.z;
            acc.w += vv * e.w;
        }
    }
    acc.x += __shfl_xor(acc.x, 16);
    acc.y += __shfl_xor(acc.y, 16);
    acc.z += __shfl_xor(acc.z, 16);
    acc.w += __shfl_xor(acc.w, 16);
    acc.x += __shfl_xor(acc.x, 32);
    acc.y += __shfl_xor(acc.y, 32);
    acc.z += __shfl_xor(acc.z, 32);
    acc.w += __shfl_xor(acc.w, 32);
    if (lane < 16) Eout[r * 16 + lane] = acc;
}

// ---------------- gather batch rows into out (init or accumulate), float4 ----
__global__ void k_gather(const int* __restrict__ bu, const int* __restrict__ bp,
                         const int* __restrict__ bn, const float4* __restrict__ E,
                         float4* __restrict__ out, int init) {
    int idx = blockIdx.x * blockDim.x + threadIdx.x;
    if (idx >= 3 * BATCH * 16) return;
    int j = idx >> 4;
    int d = idx & 15;
    int node;
    if (j < BATCH)          node = bu[j];
    else if (j < 2 * BATCH) node = N_USERS + bp[j - BATCH];
    else                    node = N_USERS + bn[j - 2 * BATCH];
    float4 v = E[node * 16 + d];
    v.x *= 0.25f; v.y *= 0.25f; v.z *= 0.25f; v.w *= 0.25f;
    if (init) {
        out[idx] = v;
    } else {
        float4 o = out[idx];
        o.x += v.x; o.y += v.y; o.z += v.z; o.w += v.w;
        out[idx] = o;
    }
}

extern "C" void kernel_launch(void* const* d_in, const int* in_sizes, int n_in,
                              void* d_out, int out_size, void* d_ws, size_t ws_size,
                              hipStream_t stream) {
    const int*   bu   = (const int*)d_in[0];
    const int*   bp   = (const int*)d_in[1];
    const int*   bn   = (const int*)d_in[2];
    const float* eu   = (const float*)d_in[3];
    const float* ei   = (const float*)d_in[4];
    const int*   row  = (const int*)d_in[5];
    const int*   col  = (const int*)d_in[6];
    const float* vals = (const float*)d_in[7];
    float* out = (float*)d_out;

    char* p = (char*)d_ws;
    auto alloc = [&](size_t nbytes) {
        void* r = (void*)p;
        p += (nbytes + 255) & ~(size_t)255;
        return r;
    };
    float*              E_a     = (float*)alloc((size_t)N_NODES * EMBED * 4);
    float*              E_b     = (float*)alloc((size_t)N_NODES * EMBED * 4);
    unsigned long long* edges   = (unsigned long long*)alloc((size_t)NNZV * 8);
    unsigned long long* staging = (unsigned long long*)alloc((size_t)NNZV * 8);
    int*                row_ptr = (int*)alloc((N_NODES + 1) * 4);
    int*                cursor  = (int*)alloc(N_NODES * 4);
    int*                counts  = (int*)alloc(N_NODES * 4);
    int*                bcur    = (int*)alloc(512 * 4);
    int*                bsums   = (int*)alloc(256 * 4);
    int*                bscan   = (int*)alloc(256 * 4);
    (void)ws_size; (void)n_in; (void)in_sizes; (void)out_size;

    const int nnz = NNZV;
    hipMemsetAsync(counts, 0, N_NODES * sizeof(int), stream);

    k_concat<<<(N_NODES * (EMBED / 4) + 255) / 256, 256, 0, stream>>>(eu, ei, E_a);
    k_hist<<<(nnz + 255) / 256, 256, 0, stream>>>(row, counts, nnz);

    int nb = (N_NODES + 1023) / 1024;
    k_scan_blocks<<<nb, 256, 0, stream>>>(counts, row_ptr, bsums, N_NODES);
    k_scan_sums<<<1, 256, 0, stream>>>(bsums, bscan, nb);
    k_add<<<(N_NODES + 255) / 256, 256, 0, stream>>>(row_ptr, cursor, bcur, bscan, N_NODES, nnz);

    k_parta<<<(nnz + 16383) / 16384, 512, 0, stream>>>(row, col, vals, bcur, staging, nnz);
    k_partb<<<NBKT, 256, 0, stream>>>(row_ptr, staging, cursor, edges);

    k_gather<<<(3 * BATCH * 16 + 255) / 256, 256, 0, stream>>>(
        bu, bp, bn, (const float4*)E_a, (float4*)out, 1);

    float* cur = E_a;
    float* nxt = E_b;
    for (int l = 0; l < 3; l++) {
        k_spmm<<<(N_NODES + 3) / 4, 256, 0, stream>>>(
            row_ptr, edges, (const float4*)cur, (float4*)nxt);
        k_gather<<<(3 * BATCH * 16 + 255) / 256, 256, 0, stream>>>(
            bu, bp, bn, (const float4*)nxt, (float4*)out, 0);
        float* t = cur; cur = nxt; nxt = t;
    }
}

// Round 5
// 655.054 us; speedup vs baseline: 1.8977x; 1.3200x over previous
//
#include <hip/hip_runtime.h>

#define N_USERS 100000
#define N_ITEMS 50000
#define N_NODES 150000
#define EMBED   64
#define NNZV    4000000
#define BATCH   4096
// bucket = row >> 9 : 512 rows per bucket, ceil(150000/512) = 293 buckets
#define NBKT    293
// fixed staging capacity per bucket: mean 13,653 + ~21 sigma (sigma ~117)
#define CAP     16128

// ---------------- concat embed_user | embed_item -> E (float4 vectorized) ----
__global__ void k_concat(const float* __restrict__ eu, const float* __restrict__ ei,
                         float* __restrict__ E) {
    int idx = blockIdx.x * blockDim.x + threadIdx.x;       // float4 index
    const int total = N_NODES * (EMBED / 4);
    if (idx >= total) return;
    int node = idx / (EMBED / 4);
    int part = idx - node * (EMBED / 4);
    float4 v;
    if (node < N_USERS) v = ((const float4*)eu)[node * (EMBED / 4) + part];
    else                v = ((const float4*)ei)[(node - N_USERS) * (EMBED / 4) + part];
    ((float4*)E)[idx] = v;
}

// ---------------- Phase A: partition edges into 512-row buckets --------------
// Record: low32 = (r&511)<<18 | col (col < 150000 < 2^18), high32 = val bits.
// Fixed-capacity staging slots (no row_ptr needed yet): bucket b's records go
// at staging[b*CAP + bcnt-reservation]. Only ~71K global atomics total.
__global__ __launch_bounds__(512) void k_parta(
        const int* __restrict__ row, const int* __restrict__ col,
        const float* __restrict__ vals, int* __restrict__ bcnt,
        unsigned long long* __restrict__ staging, int nnz) {
    __shared__ int cnt[512];
    __shared__ int base_s[512];
    int tid = threadIdx.x;
    cnt[tid] = 0;
    __syncthreads();
    int tile0 = blockIdx.x * 16384;
    for (int k = 0; k < 32; k++) {
        int e = tile0 + k * 512 + tid;
        if (e < nnz) atomicAdd(&cnt[row[e] >> 9], 1);
    }
    __syncthreads();
    int c_ = cnt[tid];
    base_s[tid] = c_ ? (tid * CAP + atomicAdd(&bcnt[tid], c_)) : 0;
    __syncthreads();
    cnt[tid] = 0;                                       // reuse as rank counter
    __syncthreads();
    for (int k = 0; k < 32; k++) {
        int e = tile0 + k * 512 + tid;
        if (e < nnz) {
            int r = row[e];
            int b = r >> 9;
            int rank = atomicAdd(&cnt[b], 1);
            unsigned int key = ((unsigned int)(r & 511) << 18) | (unsigned int)col[e];
            unsigned long long rec = (unsigned long long)key
                                   | ((unsigned long long)__float_as_uint(vals[e]) << 32);
            staging[base_s[b] + rank] = rec;
        }
    }
}

// ---------------- scan of bucket counts -> bucket bases (single block) -------
__global__ __launch_bounds__(512) void k_bscan(const int* __restrict__ bcnt,
                                               int* __restrict__ bbase,
                                               int* __restrict__ row_ptr, int nnz) {
    __shared__ int s[512];
    int t = threadIdx.x;
    int v = (t < NBKT) ? bcnt[t] : 0;
    s[t] = v;
    __syncthreads();
    for (int off = 1; off < 512; off <<= 1) {
        int u = (t >= off) ? s[t - off] : 0;
        __syncthreads();
        s[t] += u;
        __syncthreads();
    }
    bbase[t] = s[t] - v;       // exclusive
    if (t == 0) row_ptr[N_NODES] = nnz;
}

// ---------------- Phase B: per-bucket LDS histogram + scan + local scatter ---
// One block per bucket. All per-row counting is LDS atomics; writes row_ptr
// for its 512 rows and scatters records into the bucket's contiguous edges
// window (~110 KB -> lines fill inside one XCD's L2).
__global__ __launch_bounds__(512) void k_partb(
        const int* __restrict__ bcnt, const int* __restrict__ bbase,
        const unsigned long long* __restrict__ staging,
        int* __restrict__ row_ptr,
        unsigned long long* __restrict__ edges) {
    __shared__ int cnt[512];
    __shared__ int s[512];
    __shared__ int cur[512];
    int b = blockIdx.x;
    int t = threadIdx.x;
    int n    = bcnt[b];
    int base = bbase[b];
    const unsigned long long* sb = staging + (size_t)b * CAP;

    cnt[t] = 0;
    __syncthreads();
    for (int i = t; i < n; i += 512)
        atomicAdd(&cnt[(unsigned int)sb[i] >> 18], 1);
    __syncthreads();
    int v = cnt[t];
    s[t] = v;
    __syncthreads();
    for (int off = 1; off < 512; off <<= 1) {
        int u = (t >= off) ? s[t - off] : 0;
        __syncthreads();
        s[t] += u;
        __syncthreads();
    }
    int excl = s[t] - v;
    cur[t] = excl;
    int r = (b << 9) + t;
    if (r < N_NODES) row_ptr[r] = base + excl;
    __syncthreads();
    for (int i = t; i < n; i += 512) {
        unsigned long long rec = sb[i];
        unsigned int key = (unsigned int)rec;
        int rank = atomicAdd(&cur[key >> 18], 1);
        edges[base + rank] = (rec & 0xFFFFFFFF00000000ull) | (key & 0x3FFFFu);
    }
}

// ---------------- SpMM: wave per row, quarter-wave (16 lanes) per edge -------
// Inner trip count kmax is WAVE-UNIFORM: on AMD, __shfl (ds_bpermute) from
// INACTIVE lanes returns 0 (round-2 bug). Overshoot lanes hold zero-padded
// records (vv==0) so extra iterations are harmless.
__global__ void k_spmm(const int* __restrict__ row_ptr,
                       const unsigned long long* __restrict__ edges,
                       const float4* __restrict__ Ein, float4* __restrict__ Eout) {
    int lane = threadIdx.x & 63;
    int r = blockIdx.x * 4 + (threadIdx.x >> 6);
    if (r >= N_NODES) return;
    int g = lane >> 4;
    int d = lane & 15;
    int start = row_ptr[r];
    int end   = row_ptr[r + 1];
    float4 acc = make_float4(0.f, 0.f, 0.f, 0.f);
    for (int e0 = start; e0 < end; e0 += 64) {
        int ei = e0 + lane;
        unsigned long long rec = 0ull;
        if (ei < end) rec = edges[ei];
        int clo = (int)(rec & 0xffffffffull);
        int vhi = (int)(rec >> 32);
        int nleft = end - e0;
        int kmax = (nleft + 3) >> 2;          // uniform across the wave
        #pragma unroll 4
        for (int k = 0; k < kmax; k++) {
            int src = 4 * k + g;
            int cc = __shfl(clo, src);
            float vv = __int_as_float(__shfl(vhi, src));
            float4 e = Ein[cc * 16 + d];
            acc.x += vv * e.x;
            acc.y += vv * e.y;
            acc.z += vv * e.z;
            acc.w += vv * e.w;
        }
    }
    acc.x += __shfl_xor(acc.x, 16);
    acc.y += __shfl_xor(acc.y, 16);
    acc.z += __shfl_xor(acc.z, 16);
    acc.w += __shfl_xor(acc.w, 16);
    acc.x += __shfl_xor(acc.x, 32);
    acc.y += __shfl_xor(acc.y, 32);
    acc.z += __shfl_xor(acc.z, 32);
    acc.w += __shfl_xor(acc.w, 32);
    if (lane < 16) Eout[r * 16 + lane] = acc;
}

// ---------------- gather batch rows into out (init or accumulate), float4 ----
__global__ void k_gather(const int* __restrict__ bu, const int* __restrict__ bp,
                         const int* __restrict__ bn, const float4* __restrict__ E,
                         float4* __restrict__ out, int init) {
    int idx = blockIdx.x * blockDim.x + threadIdx.x;
    if (idx >= 3 * BATCH * 16) return;
    int j = idx >> 4;
    int d = idx & 15;
    int node;
    if (j < BATCH)          node = bu[j];
    else if (j < 2 * BATCH) node = N_USERS + bp[j - BATCH];
    else                    node = N_USERS + bn[j - 2 * BATCH];
    float4 v = E[node * 16 + d];
    v.x *= 0.25f; v.y *= 0.25f; v.z *= 0.25f; v.w *= 0.25f;
    if (init) {
        out[idx] = v;
    } else {
        float4 o = out[idx];
        o.x += v.x; o.y += v.y; o.z += v.z; o.w += v.w;
        out[idx] = o;
    }
}

extern "C" void kernel_launch(void* const* d_in, const int* in_sizes, int n_in,
                              void* d_out, int out_size, void* d_ws, size_t ws_size,
                              hipStream_t stream) {
    const int*   bu   = (const int*)d_in[0];
    const int*   bp   = (const int*)d_in[1];
    const int*   bn   = (const int*)d_in[2];
    const float* eu   = (const float*)d_in[3];
    const float* ei   = (const float*)d_in[4];
    const int*   row  = (const int*)d_in[5];
    const int*   col  = (const int*)d_in[6];
    const float* vals = (const float*)d_in[7];
    float* out = (float*)d_out;

    char* p = (char*)d_ws;
    auto alloc = [&](size_t nbytes) {
        void* r = (void*)p;
        p += (nbytes + 255) & ~(size_t)255;
        return r;
    };
    float*              E_a     = (float*)alloc((size_t)N_NODES * EMBED * 4);
    float*              E_b     = (float*)alloc((size_t)N_NODES * EMBED * 4);
    unsigned long long* edges   = (unsigned long long*)alloc((size_t)NNZV * 8);
    int*                row_ptr = (int*)alloc((N_NODES + 1) * 4);
    int*                bcnt    = (int*)alloc(512 * 4);
    int*                bbase   = (int*)alloc(512 * 4);
    (void)ws_size; (void)n_in; (void)in_sizes; (void)out_size;

    // staging (NBKT*CAP*8 = 37.8 MB) overlays E_b (38.4 MB): staging is dead
    // before the first k_spmm writes E_b (same stream => ordered).
    unsigned long long* staging = (unsigned long long*)E_b;

    const int nnz = NNZV;
    hipMemsetAsync(bcnt, 0, 512 * sizeof(int), stream);

    k_concat<<<(N_NODES * (EMBED / 4) + 255) / 256, 256, 0, stream>>>(eu, ei, E_a);

    k_parta<<<(nnz + 16383) / 16384, 512, 0, stream>>>(row, col, vals, bcnt, staging, nnz);
    k_bscan<<<1, 512, 0, stream>>>(bcnt, bbase, row_ptr, nnz);
    k_partb<<<NBKT, 512, 0, stream>>>(bcnt, bbase, staging, row_ptr, edges);

    k_gather<<<(3 * BATCH * 16 + 255) / 256, 256, 0, stream>>>(
        bu, bp, bn, (const float4*)E_a, (float4*)out, 1);

    float* cur = E_a;
    float* nxt = E_b;
    for (int l = 0; l < 3; l++) {
        k_spmm<<<(N_NODES + 3) / 4, 256, 0, stream>>>(
            row_ptr, edges, (const float4*)cur, (float4*)nxt);
        k_gather<<<(3 * BATCH * 16 + 255) / 256, 256, 0, stream>>>(
            bu, bp, bn, (const float4*)nxt, (float4*)out, 0);
        float* t = cur; cur = nxt; nxt = t;
    }
}

// Round 6
// 520.395 us; speedup vs baseline: 2.3887x; 1.2588x over previous
//
#include <hip/hip_runtime.h>

#define N_USERS 100000
#define N_ITEMS 50000
#define N_NODES 150000
#define EMBED   64
#define NNZV    4000000
#define BATCH   4096
// bucket = row >> 9 : 512 rows per bucket, ceil(150000/512) = 293 buckets
#define NBKT    293
// fixed staging capacity per bucket: mean 13,653 + ~21 sigma
#define CAP     16128

// ---------------- Phase A: partition edges into 512-row buckets --------------
// Record: low32 = (r&511)<<18 | col (col < 150000 < 2^18), high32 = val bits.
// Fixed-capacity staging slots: bucket b's records go at
// staging[b*CAP + reservation]. Only ~71K global atomics total.
__global__ __launch_bounds__(512) void k_parta(
        const int* __restrict__ row, const int* __restrict__ col,
        const float* __restrict__ vals, int* __restrict__ bcnt,
        unsigned long long* __restrict__ staging, int nnz) {
    __shared__ int cnt[512];
    __shared__ int base_s[512];
    int tid = threadIdx.x;
    cnt[tid] = 0;
    __syncthreads();
    int tile0 = blockIdx.x * 16384;
    for (int k = 0; k < 32; k++) {
        int e = tile0 + k * 512 + tid;
        if (e < nnz) atomicAdd(&cnt[row[e] >> 9], 1);
    }
    __syncthreads();
    int c_ = cnt[tid];
    base_s[tid] = c_ ? (tid * CAP + atomicAdd(&bcnt[tid], c_)) : 0;
    __syncthreads();
    cnt[tid] = 0;                                       // reuse as rank counter
    __syncthreads();
    for (int k = 0; k < 32; k++) {
        int e = tile0 + k * 512 + tid;
        if (e < nnz) {
            int r = row[e];
            int b = r >> 9;
            int rank = atomicAdd(&cnt[b], 1);
            unsigned int key = ((unsigned int)(r & 511) << 18) | (unsigned int)col[e];
            unsigned long long rec = (unsigned long long)key
                                   | ((unsigned long long)__float_as_uint(vals[e]) << 32);
            staging[base_s[b] + rank] = rec;
        }
    }
}

// ------- Phase B: bucket scan + per-bucket histogram/scan + local scatter ----
// One block per bucket. Each block redundantly scans the 293 bucket counts
// (cheap) to get its base; then LDS histogram of its 512 rows, LDS scan,
// writes row_ptr, scatters records into the bucket's contiguous edges window
// (~110 KB -> lines fill inside one XCD's L2).
__global__ __launch_bounds__(512) void k_partb(
        const int* __restrict__ bcnt,
        const unsigned long long* __restrict__ staging,
        int* __restrict__ row_ptr,
        unsigned long long* __restrict__ edges) {
    __shared__ int s[512];
    __shared__ int cnt[512];
    __shared__ int cur[512];
    __shared__ int base_sh;
    int b = blockIdx.x;
    int t = threadIdx.x;

    // exclusive prefix of bucket counts at position b
    int v = (t < NBKT) ? bcnt[t] : 0;
    s[t] = v;
    __syncthreads();
    for (int off = 1; off < 512; off <<= 1) {
        int u = (t >= off) ? s[t - off] : 0;
        __syncthreads();
        s[t] += u;
        __syncthreads();
    }
    if (t == b) base_sh = s[t] - v;
    if (b == 0 && t == 0) row_ptr[N_NODES] = NNZV;
    __syncthreads();
    int base = base_sh;
    int n    = bcnt[b];
    const unsigned long long* sb = staging + (size_t)b * CAP;

    cnt[t] = 0;
    __syncthreads();
    for (int i = t; i < n; i += 512)
        atomicAdd(&cnt[(unsigned int)sb[i] >> 18], 1);
    __syncthreads();
    int c = cnt[t];
    s[t] = c;
    __syncthreads();
    for (int off = 1; off < 512; off <<= 1) {
        int u = (t >= off) ? s[t - off] : 0;
        __syncthreads();
        s[t] += u;
        __syncthreads();
    }
    int excl = s[t] - c;
    cur[t] = excl;
    int r = (b << 9) + t;
    if (r < N_NODES) row_ptr[r] = base + excl;
    __syncthreads();
    for (int i = t; i < n; i += 512) {
        unsigned long long rec = sb[i];
        unsigned int key = (unsigned int)rec;
        int rank = atomicAdd(&cur[key >> 18], 1);
        edges[base + rank] = (rec & 0xFFFFFFFF00000000ull) | (key & 0x3FFFFu);
    }
}

// ---------------- SpMM core macro-ish helper ---------------------------------
// Wave per row, quarter-wave (16 lanes) per edge. Inner trip count kmax is
// WAVE-UNIFORM: __shfl (ds_bpermute) from INACTIVE lanes returns 0 (round-2
// bug). Overshoot lanes hold zero-padded records (vv==0): harmless.
__device__ __forceinline__ float4 spmm_row(const int* row_ptr,
                                           const unsigned long long* edges,
                                           const float4* __restrict__ eu4,
                                           const float4* __restrict__ ei4s, // ei4 - N_USERS*16 (pre-shifted)
                                           int r, int lane) {
    int g = lane >> 4;
    int d = lane & 15;
    int start = row_ptr[r];
    int end   = row_ptr[r + 1];
    float4 acc = make_float4(0.f, 0.f, 0.f, 0.f);
    for (int e0 = start; e0 < end; e0 += 64) {
        int ei = e0 + lane;
        unsigned long long rec = 0ull;
        if (ei < end) rec = edges[ei];
        int clo = (int)(rec & 0xffffffffull);
        int vhi = (int)(rec >> 32);
        int nleft = end - e0;
        int kmax = (nleft + 3) >> 2;          // uniform across the wave
        #pragma unroll 4
        for (int k = 0; k < kmax; k++) {
            int src = 4 * k + g;
            int cc = __shfl(clo, src);
            float vv = __int_as_float(__shfl(vhi, src));
            const float4* basep = (cc < N_USERS) ? eu4 : ei4s;  // branchless select
            float4 e = basep[cc * 16 + d];
            acc.x += vv * e.x;
            acc.y += vv * e.y;
            acc.z += vv * e.z;
            acc.w += vv * e.w;
        }
    }
    acc.x += __shfl_xor(acc.x, 16);
    acc.y += __shfl_xor(acc.y, 16);
    acc.z += __shfl_xor(acc.z, 16);
    acc.w += __shfl_xor(acc.w, 16);
    acc.x += __shfl_xor(acc.x, 32);
    acc.y += __shfl_xor(acc.y, 32);
    acc.z += __shfl_xor(acc.z, 32);
    acc.w += __shfl_xor(acc.w, 32);
    return acc;
}

// ---------------- layer-1 SpMM: reads virtual concat(eu,ei), writes E1 -------
__global__ void k_spmm1(const int* __restrict__ row_ptr,
                        const unsigned long long* __restrict__ edges,
                        const float4* __restrict__ eu4,
                        const float4* __restrict__ ei4s,
                        float4* __restrict__ Eout) {
    int lane = threadIdx.x & 63;
    int r = blockIdx.x * 4 + (threadIdx.x >> 6);
    if (r >= N_NODES) return;
    float4 acc = spmm_row(row_ptr, edges, eu4, ei4s, r, lane);
    if (lane < 16) Eout[r * 16 + (lane & 15)] = acc;
}

// ---------------- generic SpMM: E_in -> E_out (layer 2) ----------------------
__global__ void k_spmm(const int* __restrict__ row_ptr,
                       const unsigned long long* __restrict__ edges,
                       const float4* __restrict__ Ein,
                       float4* __restrict__ Eout) {
    int lane = threadIdx.x & 63;
    int r = blockIdx.x * 4 + (threadIdx.x >> 6);
    if (r >= N_NODES) return;
    float4 acc = spmm_row(row_ptr, edges, Ein, Ein, r, lane);  // both branches same
    if (lane < 16) Eout[r * 16 + (lane & 15)] = acc;
}

// --------- layer-3 SpMM restricted to batch rows, fused into out -------------
// E3 is only consumed at the 12,288 batch slots: compute just those rows and
// accumulate 0.25*row directly into out. Kills 92% of layer-3 gather traffic.
__global__ void k_spmm_batch(const int* __restrict__ row_ptr,
                             const unsigned long long* __restrict__ edges,
                             const float4* __restrict__ Ein,
                             const int* __restrict__ bu, const int* __restrict__ bp,
                             const int* __restrict__ bn,
                             float4* __restrict__ out) {
    int lane = threadIdx.x & 63;
    int j = blockIdx.x * 4 + (threadIdx.x >> 6);
    if (j >= 3 * BATCH) return;
    int r;
    if (j < BATCH)          r = bu[j];
    else if (j < 2 * BATCH) r = N_USERS + bp[j - BATCH];
    else                    r = N_USERS + bn[j - 2 * BATCH];
    float4 acc = spmm_row(row_ptr, edges, Ein, Ein, r, lane);
    if (lane < 16) {
        float4 o = out[j * 16 + lane];
        o.x += 0.25f * acc.x;
        o.y += 0.25f * acc.y;
        o.z += 0.25f * acc.z;
        o.w += 0.25f * acc.w;
        out[j * 16 + lane] = o;
    }
}

// ---------------- init gather: out = 0.25 * E0[batch] (virtual concat) -------
__global__ void k_gather_init(const int* __restrict__ bu, const int* __restrict__ bp,
                              const int* __restrict__ bn,
                              const float4* __restrict__ eu4,
                              const float4* __restrict__ ei4s,
                              float4* __restrict__ out) {
    int idx = blockIdx.x * blockDim.x + threadIdx.x;
    if (idx >= 3 * BATCH * 16) return;
    int j = idx >> 4;
    int d = idx & 15;
    int node;
    if (j < BATCH)          node = bu[j];
    else if (j < 2 * BATCH) node = N_USERS + bp[j - BATCH];
    else                    node = N_USERS + bn[j - 2 * BATCH];
    const float4* basep = (node < N_USERS) ? eu4 : ei4s;
    float4 v = basep[node * 16 + d];
    v.x *= 0.25f; v.y *= 0.25f; v.z *= 0.25f; v.w *= 0.25f;
    out[idx] = v;
}

// ---------------- accumulate gather: out += 0.25 * E[batch] ------------------
__global__ void k_gather_acc(const int* __restrict__ bu, const int* __restrict__ bp,
                             const int* __restrict__ bn, const float4* __restrict__ E,
                             float4* __restrict__ out) {
    int idx = blockIdx.x * blockDim.x + threadIdx.x;
    if (idx >= 3 * BATCH * 16) return;
    int j = idx >> 4;
    int d = idx & 15;
    int node;
    if (j < BATCH)          node = bu[j];
    else if (j < 2 * BATCH) node = N_USERS + bp[j - BATCH];
    else                    node = N_USERS + bn[j - 2 * BATCH];
    float4 v = E[node * 16 + d];
    float4 o = out[idx];
    o.x += 0.25f * v.x; o.y += 0.25f * v.y; o.z += 0.25f * v.z; o.w += 0.25f * v.w;
    out[idx] = o;
}

extern "C" void kernel_launch(void* const* d_in, const int* in_sizes, int n_in,
                              void* d_out, int out_size, void* d_ws, size_t ws_size,
                              hipStream_t stream) {
    const int*   bu   = (const int*)d_in[0];
    const int*   bp   = (const int*)d_in[1];
    const int*   bn   = (const int*)d_in[2];
    const float* eu   = (const float*)d_in[3];
    const float* ei   = (const float*)d_in[4];
    const int*   row  = (const int*)d_in[5];
    const int*   col  = (const int*)d_in[6];
    const float* vals = (const float*)d_in[7];
    float* out = (float*)d_out;

    char* p = (char*)d_ws;
    auto alloc = [&](size_t nbytes) {
        void* r = (void*)p;
        p += (nbytes + 255) & ~(size_t)255;
        return r;
    };
    float*              E_a     = (float*)alloc((size_t)N_NODES * EMBED * 4);
    float*              E_b     = (float*)alloc((size_t)N_NODES * EMBED * 4);
    unsigned long long* edges   = (unsigned long long*)alloc((size_t)NNZV * 8);
    int*                row_ptr = (int*)alloc((N_NODES + 1) * 4);
    int*                bcnt    = (int*)alloc(512 * 4);
    (void)ws_size; (void)n_in; (void)in_sizes; (void)out_size;

    // staging (NBKT*CAP*8 = 37.8 MB) overlays E_b (38.4 MB): staging is dead
    // after k_partb, before k_spmm (layer 2) writes E_b (same stream order).
    unsigned long long* staging = (unsigned long long*)E_b;

    const float4* eu4  = (const float4*)eu;
    const float4* ei4s = (const float4*)ei - (size_t)N_USERS * 16;  // pre-shifted

    const int nnz = NNZV;
    hipMemsetAsync(bcnt, 0, 512 * sizeof(int), stream);

    k_parta<<<(nnz + 16383) / 16384, 512, 0, stream>>>(row, col, vals, bcnt, staging, nnz);
    k_partb<<<NBKT, 512, 0, stream>>>(bcnt, staging, row_ptr, edges);

    // out = 0.25 * E0[batch]
    k_gather_init<<<(3 * BATCH * 16 + 255) / 256, 256, 0, stream>>>(
        bu, bp, bn, eu4, ei4s, (float4*)out);

    // layer 1: E1 = A * E0 (virtual concat input)
    k_spmm1<<<(N_NODES + 3) / 4, 256, 0, stream>>>(row_ptr, edges, eu4, ei4s, (float4*)E_a);
    k_gather_acc<<<(3 * BATCH * 16 + 255) / 256, 256, 0, stream>>>(
        bu, bp, bn, (const float4*)E_a, (float4*)out);

    // layer 2: E2 = A * E1
    k_spmm<<<(N_NODES + 3) / 4, 256, 0, stream>>>(row_ptr, edges, (const float4*)E_a, (float4*)E_b);
    k_gather_acc<<<(3 * BATCH * 16 + 255) / 256, 256, 0, stream>>>(
        bu, bp, bn, (const float4*)E_b, (float4*)out);

    // layer 3: only batch rows, fused into out
    k_spmm_batch<<<(3 * BATCH + 3) / 4, 256, 0, stream>>>(
        row_ptr, edges, (const float4*)E_b, bu, bp, bn, (float4*)out);
}